// Round 3
// baseline (68.034 us; speedup 1.0000x reference)
//
#include <hip/hip_runtime.h>

// out[b][o] = sum_{i,m} a0[b,i]*D[b,m]*T[i][m][o],  D[b,m]=a1*a2*a3, m=(j,k,l)
// K = 33^4 ~ 1.19M streamed once through v_mfma_f32_32x32x16_bf16.
#define HSZ 32
#define HP1 33
#define M3 35937            // 33^3
#define TI_STRIDE 1149984   // 33^3 * 32 floats (T stride over i)
#define NBLK 1124           // blocks; each does NCH chunks of 16 m's
#define NCH 2               // 1124*2*16 = 35968 >= M3 (tail zero-padded via df)

typedef short bf16x8 __attribute__((ext_vector_type(8)));
typedef float f32x16 __attribute__((ext_vector_type(16)));

__device__ inline short f2bf(float f) {
  unsigned u = __builtin_bit_cast(unsigned, f);
  u += 0x7FFFu + ((u >> 16) & 1u);  // round-to-nearest-even
  return (short)(u >> 16);
}

// one wave per block. lane l: bo = l&31 (A-row=b / B-col=o), g = l>>5 (k-group)
__global__ __launch_bounds__(64) void k_main(const float* __restrict__ T,
                                             const float* __restrict__ nh,
                                             float* __restrict__ tiles) {
  const int l = (int)threadIdx.x;
  const int bo = l & 31;
  const int g = l >> 5;
  f32x16 acc = {};

  for (int c = 0; c < NCH; ++c) {
    const int m0 = ((int)blockIdx.x * NCH + c) * 16;

    // On-the-fly A-side fragment df[e] = D[bo][m0+8g+e] and T column offsets.
    float df[8];
    int ioff[8];
#pragma unroll
    for (int e = 0; e < 8; ++e) {
      const int mm = m0 + 8 * g + e;
      const bool valid = mm < M3;
      const int mc = valid ? mm : (M3 - 1);
      const int j = mc / 1089;
      const int r = mc - j * 1089;
      const int kk = r / 33;
      const int ll = r - kk * 33;
      const float a1 = (j < HSZ) ? nh[(bo * 4 + 1) * HSZ + j] : 1.0f;
      const float a2 = (kk < HSZ) ? nh[(bo * 4 + 2) * HSZ + kk] : 1.0f;
      const float a3 = (ll < HSZ) ? nh[(bo * 4 + 3) * HSZ + ll] : 1.0f;
      df[e] = valid ? (a1 * a2 * a3) : 0.0f;
      ioff[e] = mc * 32 + bo;
    }

#define LOADT(buf, row)                                   \
  {                                                       \
    const float* Tp = T + (size_t)(row) * TI_STRIDE;      \
    _Pragma("unroll")                                     \
    for (int e = 0; e < 8; ++e) buf[e] = Tp[ioff[e]];     \
  }
#define COMP(buf, a0v)                                                     \
  {                                                                        \
    bf16x8 af, bfr;                                                        \
    _Pragma("unroll")                                                      \
    for (int e = 0; e < 8; ++e) {                                          \
      af[e] = f2bf((a0v) * df[e]);                                         \
      bfr[e] = f2bf(buf[e]);                                               \
    }                                                                      \
    acc = __builtin_amdgcn_mfma_f32_32x32x16_bf16(af, bfr, acc, 0, 0, 0);  \
  }

    // 3-buffer distance-2 software pipeline over i = 0..32
    float tA[8], tB[8], tC[8];
    float aA, aB, aC;
    LOADT(tA, 0);
    aA = nh[bo * 128 + 0];
    LOADT(tB, 1);
    aB = nh[bo * 128 + 1];
    for (int i = 0; i < 30; i += 3) {  // computes i..i+2 for i=0,3,...,27
      LOADT(tC, i + 2);
      aC = nh[bo * 128 + i + 2];       // i+2 <= 29 < 32, always a real load
      COMP(tA, aA);
      LOADT(tA, i + 3);
      aA = nh[bo * 128 + i + 3];       // <= 30
      COMP(tB, aB);
      LOADT(tB, i + 4);
      aB = nh[bo * 128 + i + 4];       // <= 31
      COMP(tC, aC);
    }
    // tA holds i=30, tB holds i=31; i=32 is the bias row (a0 = 1)
    LOADT(tC, 32);
    aC = 1.0f;
    COMP(tA, aA);
    COMP(tB, aB);
    COMP(tC, aC);
#undef LOADT
#undef COMP
  }

  // store private tile; C/D layout: col=lane&31, row=(r&3)+8*(r>>2)+4*(l>>5)
  float* tp = tiles + (size_t)blockIdx.x * 1024;
#pragma unroll
  for (int r = 0; r < 16; ++r) {
    const int brow = (r & 3) + 8 * (r >> 2) + 4 * g;
    tp[brow * 32 + bo] = acc[r];
  }
}

// out[idx] = sum over NBLK tiles (4 independent accumulators; 1124 = 281*4)
__global__ __launch_bounds__(256) void k_red(const float* __restrict__ tiles,
                                             float* __restrict__ out) {
  const int idx = blockIdx.x * 256 + (int)threadIdx.x;
  float s0 = 0.f, s1 = 0.f, s2 = 0.f, s3 = 0.f;
  for (int t = 0; t < NBLK; t += 4) {
    s0 += tiles[(size_t)(t + 0) * 1024 + idx];
    s1 += tiles[(size_t)(t + 1) * 1024 + idx];
    s2 += tiles[(size_t)(t + 2) * 1024 + idx];
    s3 += tiles[(size_t)(t + 3) * 1024 + idx];
  }
  out[idx] = (s0 + s1) + (s2 + s3);
}

extern "C" void kernel_launch(void* const* d_in, const int* in_sizes, int n_in,
                              void* d_out, int out_size, void* d_ws, size_t ws_size,
                              hipStream_t stream) {
  const float* nh = (const float*)d_in[0];  // [32,4,32]
  const float* T  = (const float*)d_in[1];  // [33,33,33,33,32]
  float* out = (float*)d_out;               // [32,32] fp32
  float* tiles = (float*)d_ws;              // 1124 * 1024 floats = 4.6 MB

  k_main<<<NBLK, 64, 0, stream>>>(T, nh, tiles);
  k_red<<<4, 256, 0, stream>>>(tiles, out);
}

// Round 4
// 52.811 us; speedup vs baseline: 1.2883x; 1.2883x over previous
//
#include <hip/hip_runtime.h>

// out[b][o] = sum_{i,m} a0[b,i]*D[b,m]*T[i][m][o],  D[b,m]=a1*a2*a3, m=(j,k,l)
// K = 33^4 ~ 1.19M streamed once through v_mfma_f32_32x32x16_bf16.
// 562 blocks x 4 waves; each wave owns one 16-m chunk (2248 chunks >= 2247).
#define HSZ 32
#define HP1 33
#define M3 35937            // 33^3
#define TI_STRIDE 1149984   // 33^3 * 32 floats (T stride over i)
#define NBLK 562
#define NT 64               // shared partial tiles (zeroed via hipMemsetAsync)

typedef short bf16x8 __attribute__((ext_vector_type(8)));
typedef float f32x16 __attribute__((ext_vector_type(16)));

__device__ inline short f2bf(float f) {
  unsigned u = __builtin_bit_cast(unsigned, f);
  u += 0x7FFFu + ((u >> 16) & 1u);  // round-to-nearest-even
  return (short)(u >> 16);
}

// lane l: bo = l&31 (A-row=b / B-col=o), g = l>>5 (k-group); w = wave id.
__global__ __launch_bounds__(256) void k_main(const float* __restrict__ T,
                                              const float* __restrict__ nh,
                                              float* __restrict__ tiles) {
  __shared__ float red[4][1024];
  const int tid = (int)threadIdx.x;
  const int w = tid >> 6;
  const int l = tid & 63;
  const int bo = l & 31;
  const int g = l >> 5;
  const int m0 = ((int)blockIdx.x * 4 + w) * 16;

  // On-the-fly A-side fragment df[e] = D[bo][m0+8g+e] and T column offsets.
  float df[8];
  int ioff[8];
#pragma unroll
  for (int e = 0; e < 8; ++e) {
    const int mm = m0 + 8 * g + e;
    const bool valid = mm < M3;
    const int mc = valid ? mm : (M3 - 1);
    const int j = mc / 1089;
    const int r = mc - j * 1089;
    const int kk = r / 33;
    const int ll = r - kk * 33;
    const float a1 = (j < HSZ) ? nh[(bo * 4 + 1) * HSZ + j] : 1.0f;
    const float a2 = (kk < HSZ) ? nh[(bo * 4 + 2) * HSZ + kk] : 1.0f;
    const float a3 = (ll < HSZ) ? nh[(bo * 4 + 3) * HSZ + ll] : 1.0f;
    df[e] = valid ? (a1 * a2 * a3) : 0.0f;
    ioff[e] = mc * 32 + bo;
  }

#define LOADT(buf, row)                                   \
  {                                                       \
    const float* Tp = T + (size_t)(row) * TI_STRIDE;      \
    _Pragma("unroll")                                     \
    for (int e = 0; e < 8; ++e) buf[e] = Tp[ioff[e]];     \
  }
#define COMP(buf, a0v)                                                     \
  {                                                                        \
    bf16x8 af, bfr;                                                        \
    _Pragma("unroll")                                                      \
    for (int e = 0; e < 8; ++e) {                                          \
      af[e] = f2bf((a0v) * df[e]);                                         \
      bfr[e] = f2bf(buf[e]);                                               \
    }                                                                      \
    acc = __builtin_amdgcn_mfma_f32_32x32x16_bf16(af, bfr, acc, 0, 0, 0);  \
  }

  f32x16 acc = {};
  // 3-buffer distance-2 software pipeline over i = 0..32 (no chunk drain:
  // one chunk per wave for the whole kernel).
  float tA[8], tB[8], tC[8];
  float aA, aB, aC;
  LOADT(tA, 0);
  aA = nh[bo * 128 + 0];
  LOADT(tB, 1);
  aB = nh[bo * 128 + 1];
  for (int i = 0; i < 30; i += 3) {  // computes i..i+2 for i=0,3,...,27
    LOADT(tC, i + 2);
    aC = nh[bo * 128 + i + 2];  // i+2 <= 29, real a0
    COMP(tA, aA);
    LOADT(tA, i + 3);
    aA = nh[bo * 128 + i + 3];  // <= 30
    COMP(tB, aB);
    LOADT(tB, i + 4);
    aB = nh[bo * 128 + i + 4];  // <= 31
    COMP(tC, aC);
  }
  // tA holds i=30, tB holds i=31; i=32 is the bias row (a0 = 1)
  LOADT(tC, 32);
  COMP(tA, aA);
  COMP(tB, aB);
  COMP(tC, 1.0f);
#undef LOADT
#undef COMP

  // cross-wave reduce in LDS. C/D layout: col=lane&31,
  // row=(r&3)+8*(r>>2)+4*(lane>>5)  (verified m74/m101)
#pragma unroll
  for (int r = 0; r < 16; ++r) {
    const int brow = (r & 3) + 8 * (r >> 2) + 4 * g;
    red[w][brow * 32 + bo] = acc[r];
  }
  __syncthreads();
  const float4 s0 = *(const float4*)&red[0][tid * 4];
  const float4 s1 = *(const float4*)&red[1][tid * 4];
  const float4 s2 = *(const float4*)&red[2][tid * 4];
  const float4 s3 = *(const float4*)&red[3][tid * 4];
  float* tp = tiles + (size_t)((int)blockIdx.x & (NT - 1)) * 1024 + tid * 4;
  atomicAdd(tp + 0, (s0.x + s1.x) + (s2.x + s3.x));
  atomicAdd(tp + 1, (s0.y + s1.y) + (s2.y + s3.y));
  atomicAdd(tp + 2, (s0.z + s1.z) + (s2.z + s3.z));
  atomicAdd(tp + 3, (s0.w + s1.w) + (s2.w + s3.w));
}

// out[idx] = sum over NT=64 tiles; 1 block, float4 per thread, 8 accumulators.
__global__ __launch_bounds__(256) void k_red(const float* __restrict__ tiles,
                                             float* __restrict__ out) {
  const int tid = (int)threadIdx.x;
  float4 a[8];
#pragma unroll
  for (int q = 0; q < 8; ++q) a[q] = make_float4(0.f, 0.f, 0.f, 0.f);
  for (int t = 0; t < NT; t += 8) {
#pragma unroll
    for (int q = 0; q < 8; ++q) {
      const float4 v =
          *(const float4*)(tiles + (size_t)(t + q) * 1024 + tid * 4);
      a[q].x += v.x; a[q].y += v.y; a[q].z += v.z; a[q].w += v.w;
    }
  }
  float4 s;
  s.x = ((a[0].x + a[1].x) + (a[2].x + a[3].x)) + ((a[4].x + a[5].x) + (a[6].x + a[7].x));
  s.y = ((a[0].y + a[1].y) + (a[2].y + a[3].y)) + ((a[4].y + a[5].y) + (a[6].y + a[7].y));
  s.z = ((a[0].z + a[1].z) + (a[2].z + a[3].z)) + ((a[4].z + a[5].z) + (a[6].z + a[7].z));
  s.w = ((a[0].w + a[1].w) + (a[2].w + a[3].w)) + ((a[4].w + a[5].w) + (a[6].w + a[7].w));
  ((float4*)out)[tid] = s;
}

extern "C" void kernel_launch(void* const* d_in, const int* in_sizes, int n_in,
                              void* d_out, int out_size, void* d_ws, size_t ws_size,
                              hipStream_t stream) {
  const float* nh = (const float*)d_in[0];  // [32,4,32]
  const float* T  = (const float*)d_in[1];  // [33,33,33,33,32]
  float* out = (float*)d_out;               // [32,32] fp32
  float* tiles = (float*)d_ws;              // NT * 1024 floats = 256 KB

  hipMemsetAsync(tiles, 0, (size_t)NT * 1024 * sizeof(float), stream);
  k_main<<<NBLK, 256, 0, stream>>>(T, nh, tiles);
  k_red<<<1, 256, 0, stream>>>(tiles, out);
}

// Round 5
// 47.590 us; speedup vs baseline: 1.4296x; 1.1097x over previous
//
#include <hip/hip_runtime.h>
#include <hip/hip_bf16.h>

// out[b][o] = sum_{i,m} a0[b,i]*D[b,m]*T[i][m][o],  D[b,m]=a1*a2*a3, m=(j,k,l)
// K = 33^4 ~ 1.19M streamed once through v_mfma_f32_32x32x16_bf16.
// 2247 one-wave blocks, each owns one 16-m chunk; distance-3 load pipeline.
#define HSZ 32
#define HP1 33
#define M3 35937            // 33^3
#define TI_STRIDE 1149984   // 33^3 * 32 floats (T stride over i)
#define NBLK 2247
#define RED_BLOCKS 64

typedef short bf16x8 __attribute__((ext_vector_type(8)));
typedef float f32x16 __attribute__((ext_vector_type(16)));

__device__ inline short f2bf(float f) {
  __hip_bfloat16 h = __float2bfloat16(f);  // RTNE; compiler pairs into cvt_pk
  return __builtin_bit_cast(short, h);
}

// lane l: bo = l&31 (A-row=b / B-col=o), g = l>>5 (k-group)
__global__ __launch_bounds__(64) void k_main(const float* __restrict__ T,
                                             const float* __restrict__ nh,
                                             float* __restrict__ tiles,
                                             float* __restrict__ out) {
  __shared__ float a0s[HP1 * 32];  // a0s[i*32+b]; row 32 = 1.0 (bias)
  const int l = (int)threadIdx.x;
  const int bo = l & 31;
  const int g = l >> 5;
  const int m0 = (int)blockIdx.x * 16;

  // one-time: a0 table into LDS (conflict-free broadcast reads later)
  for (int x = l; x < HP1 * 32; x += 64) {
    const int i = x >> 5;
    const int b = x & 31;
    a0s[x] = (i < HSZ) ? nh[b * 128 + i] : 1.0f;
  }

  if (blockIdx.x == 0) {
    // zero d_out each call; k_red (later in stream) accumulates atomically
    const float4 z = make_float4(0.f, 0.f, 0.f, 0.f);
    for (int x = l; x < 256; x += 64) ((float4*)out)[x] = z;
  }

  // On-the-fly A-side fragment df[e] = D[bo][m0+8g+e] and T column offsets.
  float df[8];
  int ioff[8];
#pragma unroll
  for (int e = 0; e < 8; ++e) {
    const int mm = m0 + 8 * g + e;
    const bool valid = mm < M3;
    const int mc = valid ? mm : (M3 - 1);
    const int j = mc / 1089;
    const int r = mc - j * 1089;
    const int kk = r / 33;
    const int ll = r - kk * 33;
    const float a1 = (j < HSZ) ? nh[(bo * 4 + 1) * HSZ + j] : 1.0f;
    const float a2 = (kk < HSZ) ? nh[(bo * 4 + 2) * HSZ + kk] : 1.0f;
    const float a3 = (ll < HSZ) ? nh[(bo * 4 + 3) * HSZ + ll] : 1.0f;
    df[e] = valid ? (a1 * a2 * a3) : 0.0f;
    ioff[e] = mc * 32 + bo;
  }
  __syncthreads();

#define LOADT(buf, av, row)                               \
  {                                                       \
    const float* Tp = T + (size_t)(row) * TI_STRIDE;      \
    _Pragma("unroll")                                     \
    for (int e = 0; e < 8; ++e) buf[e] = Tp[ioff[e]];     \
    av = a0s[(row) * 32 + bo];                            \
  }
#define COMP(buf, av)                                                      \
  {                                                                        \
    bf16x8 af, bfr;                                                        \
    _Pragma("unroll")                                                      \
    for (int e = 0; e < 8; ++e) {                                          \
      af[e] = f2bf((av) * df[e]);                                          \
      bfr[e] = f2bf(buf[e]);                                               \
    }                                                                      \
    acc = __builtin_amdgcn_mfma_f32_32x32x16_bf16(af, bfr, acc, 0, 0, 0);  \
  }

  f32x16 acc = {};
  // distance-3, 4-buffer software pipeline over i = 0..32
  float t0[8], t1[8], t2[8], t3[8];
  float a0v, a1v, a2v, a3v;
  LOADT(t0, a0v, 0);
  LOADT(t1, a1v, 1);
  LOADT(t2, a2v, 2);
  for (int i = 0; i < 28; i += 4) {  // comps i..i+3 for i = 0,4,...,24
    LOADT(t3, a3v, i + 3);
    COMP(t0, a0v);
    LOADT(t0, a0v, i + 4);
    COMP(t1, a1v);
    LOADT(t1, a1v, i + 5);
    COMP(t2, a2v);
    LOADT(t2, a2v, i + 6);   // max row 30
    COMP(t3, a3v);
  }
  // after loop: t0=row28, t1=row29, t2=row30
  LOADT(t3, a3v, 31);
  COMP(t0, a0v);             // 28
  LOADT(t0, a0v, 32);        // a0v := a0s[32] row = 1.0
  COMP(t1, a1v);             // 29
  COMP(t2, a2v);             // 30
  COMP(t3, a3v);             // 31
  COMP(t0, a0v);             // 32 (bias row)
#undef LOADT
#undef COMP

  // private tile store; C/D layout: col=lane&31, row=(r&3)+8*(r>>2)+4*(l>>5)
  float* tp = tiles + (size_t)blockIdx.x * 1024;
#pragma unroll
  for (int r = 0; r < 16; ++r) {
    const int brow = (r & 3) + 8 * (r >> 2) + 4 * g;
    tp[brow * 32 + bo] = acc[r];
  }
}

// k_red: block q sums tiles {q, q+64, ...} (L2-hot), 4 atomicAdds/thread.
__global__ __launch_bounds__(256) void k_red(const float* __restrict__ tiles,
                                             float* __restrict__ out) {
  const int q = (int)blockIdx.x;
  const int tid = (int)threadIdx.x;
  float4 s0 = make_float4(0.f, 0.f, 0.f, 0.f);
  float4 s1 = make_float4(0.f, 0.f, 0.f, 0.f);
  int t = q;
  for (; t + RED_BLOCKS < NBLK; t += 2 * RED_BLOCKS) {
    const float4 v0 = *(const float4*)(tiles + (size_t)t * 1024 + tid * 4);
    const float4 v1 =
        *(const float4*)(tiles + (size_t)(t + RED_BLOCKS) * 1024 + tid * 4);
    s0.x += v0.x; s0.y += v0.y; s0.z += v0.z; s0.w += v0.w;
    s1.x += v1.x; s1.y += v1.y; s1.z += v1.z; s1.w += v1.w;
  }
  if (t < NBLK) {
    const float4 v0 = *(const float4*)(tiles + (size_t)t * 1024 + tid * 4);
    s0.x += v0.x; s0.y += v0.y; s0.z += v0.z; s0.w += v0.w;
  }
  atomicAdd(&out[tid * 4 + 0], s0.x + s1.x);
  atomicAdd(&out[tid * 4 + 1], s0.y + s1.y);
  atomicAdd(&out[tid * 4 + 2], s0.z + s1.z);
  atomicAdd(&out[tid * 4 + 3], s0.w + s1.w);
}

extern "C" void kernel_launch(void* const* d_in, const int* in_sizes, int n_in,
                              void* d_out, int out_size, void* d_ws, size_t ws_size,
                              hipStream_t stream) {
  const float* nh = (const float*)d_in[0];  // [32,4,32]
  const float* T  = (const float*)d_in[1];  // [33,33,33,33,32]
  float* out = (float*)d_out;               // [32,32] fp32
  float* tiles = (float*)d_ws;              // NBLK * 1024 floats = 9.2 MB

  k_main<<<NBLK, 64, 0, stream>>>(T, nh, tiles, out);
  k_red<<<RED_BLOCKS, 256, 0, stream>>>(tiles, out);
}